// Round 1
// baseline (903.728 us; speedup 1.0000x reference)
//
#include <hip/hip_runtime.h>
#include <math.h>

#define HH 96
#define NPIX 9216            // 96*96
#define KSPLIT 32
#define KEYS_PER_SPLIT 288   // 9216/32
#define TK 96

// ---------------------------------------------------------------- utilities

__global__ __launch_bounds__(64) void zero_stats_kernel(float* stats) {
    if (threadIdx.x < 16) stats[threadIdx.x] = 0.f;
}

// ---------------------------------------------------------------- conv3x3
// grid (6,6,ceil(Cout/4)), block (16,16). pad=1. dyn LDS: 4*Cin*9 + 18*18 floats.
__global__ __launch_bounds__(256) void conv3x3_kernel(
        const float* __restrict__ in, const float* __restrict__ w,
        float* __restrict__ out, int Cin, int Cout) {
    extern __shared__ float smem[];
    float* wl   = smem;              // [4][Cin][9]
    float* tile = smem + 4 * Cin * 9; // [18][18]

    const int tx = threadIdx.x, ty = threadIdx.y;
    const int tid = ty * 16 + tx;
    const int x0 = blockIdx.x * 16, y0 = blockIdx.y * 16;
    const int co_base = blockIdx.z * 4;
    const int nco = min(4, Cout - co_base);
    const int wcount = nco * Cin * 9;

    for (int i = tid; i < wcount; i += 256)
        wl[i] = w[co_base * Cin * 9 + i];

    float acc[4] = {0.f, 0.f, 0.f, 0.f};

    for (int ci = 0; ci < Cin; ++ci) {
        __syncthreads();
        for (int i = tid; i < 324; i += 256) {
            int r = i / 18, c = i - r * 18;
            int gy = y0 + r - 1, gx = x0 + c - 1;
            float v = 0.f;
            if (gy >= 0 && gy < HH && gx >= 0 && gx < HH)
                v = in[ci * NPIX + gy * HH + gx];
            tile[i] = v;
        }
        __syncthreads();

        float v[9];
        #pragma unroll
        for (int dy = 0; dy < 3; ++dy)
            #pragma unroll
            for (int dx = 0; dx < 3; ++dx)
                v[dy * 3 + dx] = tile[(ty + dy) * 18 + tx + dx];

        #pragma unroll
        for (int j = 0; j < 4; ++j) {
            const float* wp = wl + j * Cin * 9 + ci * 9;
            float a = acc[j];
            #pragma unroll
            for (int kk = 0; kk < 9; ++kk) a += wp[kk] * v[kk];
            acc[j] = a;
        }
    }

    const int oy = y0 + ty, ox = x0 + tx;
    #pragma unroll
    for (int j = 0; j < 4; ++j)
        if (j < nco)
            out[(co_base + j) * NPIX + oy * HH + ox] = acc[j];
}

// ---------------------------------------------------------------- layernorm
__global__ __launch_bounds__(256) void ln_reduce_kernel(
        const float* __restrict__ x, int n, float* stats) {
    float s = 0.f, s2 = 0.f;
    for (int i = blockIdx.x * 256 + threadIdx.x; i < n; i += gridDim.x * 256) {
        float v = x[i];
        s += v; s2 += v * v;
    }
    #pragma unroll
    for (int off = 32; off > 0; off >>= 1) {
        s  += __shfl_down(s,  off);
        s2 += __shfl_down(s2, off);
    }
    __shared__ float ls[4], ls2[4];
    int wid = threadIdx.x >> 6;
    if ((threadIdx.x & 63) == 0) { ls[wid] = s; ls2[wid] = s2; }
    __syncthreads();
    if (threadIdx.x == 0) {
        float a = ls[0] + ls[1] + ls[2] + ls[3];
        float b = ls2[0] + ls2[1] + ls2[2] + ls2[3];
        atomicAdd(&stats[0], a);
        atomicAdd(&stats[1], b);
    }
}

__global__ __launch_bounds__(256) void ln_apply_relu_kernel(
        float* __restrict__ x, const float* __restrict__ w,
        const float* __restrict__ b, const float* __restrict__ stats,
        int n, float inv_n) {
    int i = blockIdx.x * 256 + threadIdx.x;
    if (i >= n) return;
    float m   = stats[0] * inv_n;
    float var = stats[1] * inv_n - m * m;
    float inv = rsqrtf(var + 1e-5f);
    float t = (x[i] - m) * inv * w[i] + b[i];
    x[i] = t > 0.f ? t : 0.f;
}

// ---------------------------------------------------------------- qkv (1x1 convs with bias, 17->17)
__global__ __launch_bounds__(256) void qkv_kernel(
        const float* __restrict__ h,
        const float* __restrict__ qw, const float* __restrict__ qb,
        const float* __restrict__ kw, const float* __restrict__ kb,
        const float* __restrict__ vw, const float* __restrict__ vb,
        float* __restrict__ q, float* __restrict__ k, float* __restrict__ v) {
    int n = blockIdx.x * 256 + threadIdx.x;
    if (n >= NPIX) return;
    float hv[17];
    #pragma unroll
    for (int c = 0; c < 17; ++c) hv[c] = h[c * NPIX + n];
    #pragma unroll
    for (int co = 0; co < 17; ++co) {
        float sq = qb[co], sk = kb[co], sv = vb[co];
        #pragma unroll
        for (int ci = 0; ci < 17; ++ci) {
            float hh = hv[ci];
            sq += qw[co * 17 + ci] * hh;
            sk += kw[co * 17 + ci] * hh;
            sv += vw[co * 17 + ci] * hh;
        }
        q[co * NPIX + n] = sq;
        k[co * NPIX + n] = sk;
        v[co * NPIX + n] = sv;
    }
}

// ---------------------------------------------------------------- CAM
__global__ __launch_bounds__(256) void cam_e_kernel(const float* __restrict__ h, float* e) {
    int c = blockIdx.x / 17, d = blockIdx.x - c * 17;
    float s = 0.f;
    for (int i = threadIdx.x; i < NPIX; i += 256)
        s += h[c * NPIX + i] * h[d * NPIX + i];
    #pragma unroll
    for (int off = 32; off > 0; off >>= 1) s += __shfl_down(s, off);
    __shared__ float red[4];
    int wid = threadIdx.x >> 6;
    if ((threadIdx.x & 63) == 0) red[wid] = s;
    __syncthreads();
    if (threadIdx.x == 0) e[blockIdx.x] = red[0] + red[1] + red[2] + red[3];
}

__global__ __launch_bounds__(64) void cam_softmax_kernel(const float* __restrict__ e,
                                                         float* __restrict__ a) {
    int c = threadIdx.x;
    if (c >= 17) return;
    float rmax = -1e30f, rmin = 1e30f;
    for (int d = 0; d < 17; ++d) {
        float v = e[c * 17 + d];
        rmax = fmaxf(rmax, v);
        rmin = fminf(rmin, v);
    }
    // e_new[d] = rmax - e[c][d]; its max is rmax - rmin
    float mm = rmax - rmin;
    float p[17], sum = 0.f;
    for (int d = 0; d < 17; ++d) {
        p[d] = __expf((rmax - e[c * 17 + d]) - mm);
        sum += p[d];
    }
    float inv = 1.f / sum;
    for (int d = 0; d < 17; ++d) a[c * 17 + d] = p[d] * inv;
}

// ---------------------------------------------------------------- PAM flash attention
// grid (36, KSPLIT), block 256. one thread = one query, over this split's keys.
__global__ __launch_bounds__(256) void pam_flash_kernel(
        const float* __restrict__ q, const float* __restrict__ k,
        const float* __restrict__ v,
        float* __restrict__ m_part, float* __restrict__ l_part,
        float* __restrict__ o_part) {
    __shared__ float kt[17][TK];
    __shared__ float vt[17][TK];
    const int qi = blockIdx.x * 256 + threadIdx.x;
    const int sp = blockIdx.y;
    const int k0 = sp * KEYS_PER_SPLIT;

    float qr[17];
    #pragma unroll
    for (int c = 0; c < 17; ++c) qr[c] = q[c * NPIX + qi];

    float mr = -1e30f, lr = 0.f;
    float orr[17];
    #pragma unroll
    for (int c = 0; c < 17; ++c) orr[c] = 0.f;

    for (int t = 0; t < KEYS_PER_SPLIT / TK; ++t) {
        __syncthreads();
        for (int i = threadIdx.x; i < 17 * TK; i += 256) {
            int c = i / TK, mi = i - c * TK;
            kt[c][mi] = k[c * NPIX + k0 + t * TK + mi];
            vt[c][mi] = v[c * NPIX + k0 + t * TK + mi];
        }
        __syncthreads();
        for (int mm = 0; mm < TK; ++mm) {
            float s0 = 0.f, s1 = 0.f;
            #pragma unroll
            for (int c = 0; c < 16; c += 2) {
                s0 += qr[c]     * kt[c][mm];
                s1 += qr[c + 1] * kt[c + 1][mm];
            }
            float s = s0 + s1 + qr[16] * kt[16][mm];
            if (s > mr + 8.f) {                   // defer-max: rescale rarely
                float sc = __expf(mr - s);
                lr *= sc;
                #pragma unroll
                for (int c = 0; c < 17; ++c) orr[c] *= sc;
                mr = s;
            }
            float p = __expf(s - mr);
            lr += p;
            #pragma unroll
            for (int c = 0; c < 17; ++c) orr[c] += p * vt[c][mm];
        }
    }

    m_part[sp * NPIX + qi] = mr;
    l_part[sp * NPIX + qi] = lr;
    #pragma unroll
    for (int c = 0; c < 17; ++c)
        o_part[(sp * 17 + c) * NPIX + qi] = orr[c];
}

__global__ __launch_bounds__(256) void pam_merge_kernel(
        const float* __restrict__ m_part, const float* __restrict__ l_part,
        const float* __restrict__ o_part, const float* __restrict__ gamma,
        float* __restrict__ pam) {
    const int qi = blockIdx.x * 256 + threadIdx.x;
    float M = -1e30f;
    #pragma unroll
    for (int s = 0; s < KSPLIT; ++s) M = fmaxf(M, m_part[s * NPIX + qi]);
    float wsc[KSPLIT];
    float L = 0.f;
    #pragma unroll
    for (int s = 0; s < KSPLIT; ++s) {
        float wv = __expf(m_part[s * NPIX + qi] - M);
        wsc[s] = wv;
        L += wv * l_part[s * NPIX + qi];
    }
    float invL = gamma[0] / L;
    for (int c = 0; c < 17; ++c) {
        float acc = 0.f;
        #pragma unroll
        for (int s = 0; s < KSPLIT; ++s)
            acc += wsc[s] * o_part[(s * 17 + c) * NPIX + qi];
        pam[c * NPIX + qi] = acc * invL;
    }
}

// ---------------------------------------------------------------- combine + tail
__global__ __launch_bounds__(256) void y_combine_kernel(
        const float* __restrict__ h, const float* __restrict__ a,
        const float* __restrict__ cam_gamma, const float* __restrict__ pam,
        float* __restrict__ y) {
    int idx = blockIdx.x * 256 + threadIdx.x;
    if (idx >= 17 * NPIX) return;
    int c = idx / NPIX, n = idx - c * NPIX;
    float s = 0.f;
    #pragma unroll
    for (int d = 0; d < 17; ++d) s += a[c * 17 + d] * h[d * NPIX + n];
    y[idx] = cam_gamma[0] * s + pam[idx] + h[idx];
}

__global__ __launch_bounds__(256) void conv1x1_17_kernel(
        const float* __restrict__ in, const float* __restrict__ w,
        float* __restrict__ out) {
    int idx = blockIdx.x * 256 + threadIdx.x;
    if (idx >= 17 * NPIX) return;
    int c = idx / NPIX, n = idx - c * NPIX;
    float s = 0.f;
    #pragma unroll
    for (int ci = 0; ci < 17; ++ci) s += w[c * 17 + ci] * in[ci * NPIX + n];
    out[idx] = s;
}

// ---------------------------------------------------------------- launch

extern "C" void kernel_launch(void* const* d_in, const int* in_sizes, int n_in,
                              void* d_out, int out_size, void* d_ws, size_t ws_size,
                              hipStream_t stream) {
    const float* x       = (const float*)d_in[0];
    const float* conv1_w = (const float*)d_in[1];
    const float* ln1_w   = (const float*)d_in[2];
    const float* ln1_b   = (const float*)d_in[3];
    const float* conv2_w = (const float*)d_in[4];
    const float* ln2_w   = (const float*)d_in[5];
    const float* ln2_b   = (const float*)d_in[6];
    const float* conv3_w = (const float*)d_in[7];
    const float* ln3_w   = (const float*)d_in[8];
    const float* ln3_b   = (const float*)d_in[9];
    const float* conv4_w = (const float*)d_in[10];
    const float* ln4_w   = (const float*)d_in[11];
    const float* ln4_b   = (const float*)d_in[12];
    const float* cam_g   = (const float*)d_in[13];
    const float* q_w     = (const float*)d_in[14];
    const float* q_b     = (const float*)d_in[15];
    const float* k_w     = (const float*)d_in[16];
    const float* k_b     = (const float*)d_in[17];
    const float* v_w     = (const float*)d_in[18];
    const float* v_b     = (const float*)d_in[19];
    const float* pam_g   = (const float*)d_in[20];
    const float* conv5_w = (const float*)d_in[21];
    const float* ln5_w   = (const float*)d_in[22];
    const float* ln5_b   = (const float*)d_in[23];
    const float* conv6_w = (const float*)d_in[24];
    float* out = (float*)d_out;

    float* W = (float*)d_ws;
    float* stats  = W;                       // 16
    float* h1     = W + 16;                  // 96*9216
    float* h2     = h1 + 96 * NPIX;          // 48*9216
    float* h3     = h2 + 48 * NPIX;          // 48*9216
    float* h4     = h3 + 48 * NPIX;          // 17*9216
    float* qbuf   = h4 + 17 * NPIX;
    float* kbuf   = qbuf + 17 * NPIX;
    float* vbuf   = kbuf + 17 * NPIX;
    float* ebuf   = vbuf + 17 * NPIX;        // 289
    float* abuf   = ebuf + 289;              // 289
    float* m_part = abuf + 289;              // 32*9216
    float* l_part = m_part + KSPLIT * NPIX;  // 32*9216
    float* o_part = l_part + KSPLIT * NPIX;  // 32*17*9216
    float* pam    = o_part + KSPLIT * 17 * NPIX; // 17*9216
    float* ybuf   = pam + 17 * NPIX;         // 17*9216
    float* t5     = ybuf + 17 * NPIX;        // 17*9216

    dim3 b256(256), b16x16(16, 16);

    zero_stats_kernel<<<1, 64, 0, stream>>>(stats);

    // conv1: 237 -> 96
    {
        size_t lds = (4 * 237 * 9 + 324) * sizeof(float);
        conv3x3_kernel<<<dim3(6, 6, 24), b16x16, lds, stream>>>(x, conv1_w, h1, 237, 96);
        int n = 96 * NPIX;
        ln_reduce_kernel<<<256, b256, 0, stream>>>(h1, n, stats + 0);
        ln_apply_relu_kernel<<<(n + 255) / 256, b256, 0, stream>>>(h1, ln1_w, ln1_b, stats + 0, n, 1.f / n);
    }
    // conv2: 96 -> 48
    {
        size_t lds = (4 * 96 * 9 + 324) * sizeof(float);
        conv3x3_kernel<<<dim3(6, 6, 12), b16x16, lds, stream>>>(h1, conv2_w, h2, 96, 48);
        int n = 48 * NPIX;
        ln_reduce_kernel<<<256, b256, 0, stream>>>(h2, n, stats + 2);
        ln_apply_relu_kernel<<<(n + 255) / 256, b256, 0, stream>>>(h2, ln2_w, ln2_b, stats + 2, n, 1.f / n);
    }
    // conv3: 48 -> 48
    {
        size_t lds = (4 * 48 * 9 + 324) * sizeof(float);
        conv3x3_kernel<<<dim3(6, 6, 12), b16x16, lds, stream>>>(h2, conv3_w, h3, 48, 48);
        int n = 48 * NPIX;
        ln_reduce_kernel<<<256, b256, 0, stream>>>(h3, n, stats + 4);
        ln_apply_relu_kernel<<<(n + 255) / 256, b256, 0, stream>>>(h3, ln3_w, ln3_b, stats + 4, n, 1.f / n);
    }
    // conv4: 48 -> 17
    {
        size_t lds = (4 * 48 * 9 + 324) * sizeof(float);
        conv3x3_kernel<<<dim3(6, 6, 5), b16x16, lds, stream>>>(h3, conv4_w, h4, 48, 17);
        int n = 17 * NPIX;
        ln_reduce_kernel<<<256, b256, 0, stream>>>(h4, n, stats + 6);
        ln_apply_relu_kernel<<<(n + 255) / 256, b256, 0, stream>>>(h4, ln4_w, ln4_b, stats + 6, n, 1.f / n);
    }

    // attention inputs
    qkv_kernel<<<36, b256, 0, stream>>>(h4, q_w, q_b, k_w, k_b, v_w, v_b, qbuf, kbuf, vbuf);

    // CAM
    cam_e_kernel<<<289, b256, 0, stream>>>(h4, ebuf);
    cam_softmax_kernel<<<1, 64, 0, stream>>>(ebuf, abuf);

    // PAM
    pam_flash_kernel<<<dim3(36, KSPLIT), b256, 0, stream>>>(qbuf, kbuf, vbuf, m_part, l_part, o_part);
    pam_merge_kernel<<<36, b256, 0, stream>>>(m_part, l_part, o_part, pam_g, pam);

    // y = cam + pam + h ; conv5 ; ln5+relu ; conv6
    y_combine_kernel<<<(17 * NPIX + 255) / 256, b256, 0, stream>>>(h4, abuf, cam_g, pam, ybuf);
    conv1x1_17_kernel<<<(17 * NPIX + 255) / 256, b256, 0, stream>>>(ybuf, conv5_w, t5);
    {
        int n = 17 * NPIX;
        ln_reduce_kernel<<<256, b256, 0, stream>>>(t5, n, stats + 8);
        ln_apply_relu_kernel<<<(n + 255) / 256, b256, 0, stream>>>(t5, ln5_w, ln5_b, stats + 8, n, 1.f / n);
    }
    conv1x1_17_kernel<<<(17 * NPIX + 255) / 256, b256, 0, stream>>>(t5, conv6_w, out);
}